// Round 2
// baseline (847.976 us; speedup 1.0000x reference)
//
#include <hip/hip_runtime.h>
#include <hip/hip_bf16.h>
#include <math.h>

#define Ntok 8192
#define Dm   1024
#define Hm   2048
#define NE   8

typedef __hip_bfloat16 bf16;
typedef __attribute__((ext_vector_type(8))) short short8;
typedef __attribute__((ext_vector_type(4))) float f32x4;

static __device__ __forceinline__ float b2f(bf16 v){ return __bfloat162float(v); }
static __device__ __forceinline__ bf16  f2b(float v){ return __float2bfloat16(v); }

// ---------------- dtype detect: fp32 data has fp32-exponent <200; bf16-pairs >=~240 ----------------
__global__ void detect_kernel(const unsigned* __restrict__ xw, int* dtf)
{
    unsigned w = xw[threadIdx.x];
    int ex = (w >> 23) & 0xff;
    unsigned long long m = __ballot(ex < 200);
    if (threadIdx.x == 0) *dtf = (__popcll(m) > 32) ? 1 : 0;
}

// ---------------- gate: softmax + top-2 routing ----------------
__global__ void gate_kernel(const void* __restrict__ xv, const void* __restrict__ wgv,
                            const int* __restrict__ dtf,
                            int* cnt, float* Psum, float* wts, int* idx_buf)
{
    int fp32 = *dtf;
    int lane = threadIdx.x & 63;
    int wv   = threadIdx.x >> 6;
    int n    = blockIdx.x * 4 + wv;

    float acc[NE];
    #pragma unroll
    for (int e = 0; e < NE; e++) acc[e] = 0.f;

    if (fp32) {
        const float* xr = (const float*)xv + (size_t)n * Dm;
        const float* Wg = (const float*)wgv;
        #pragma unroll
        for (int i = 0; i < 16; i++) {
            float xval = xr[lane + 64*i];
            #pragma unroll
            for (int e = 0; e < NE; e++) acc[e] += xval * Wg[e*Dm + lane + 64*i];
        }
    } else {
        const bf16* xr = (const bf16*)xv + (size_t)n * Dm;
        const bf16* Wg = (const bf16*)wgv;
        #pragma unroll
        for (int i = 0; i < 16; i++) {
            float xval = b2f(xr[lane + 64*i]);
            #pragma unroll
            for (int e = 0; e < NE; e++) acc[e] += xval * b2f(Wg[e*Dm + lane + 64*i]);
        }
    }
    #pragma unroll
    for (int e = 0; e < NE; e++) {
        float v = acc[e];
        #pragma unroll
        for (int off = 32; off > 0; off >>= 1) v += __shfl_xor(v, off);
        acc[e] = v;
    }
    // softmax (all lanes redundantly, fp32)
    float mx = acc[0];
    #pragma unroll
    for (int e = 1; e < NE; e++) mx = fmaxf(mx, acc[e]);
    float p[NE]; float s = 0.f;
    #pragma unroll
    for (int e = 0; e < NE; e++) { p[e] = expf(acc[e] - mx); s += p[e]; }
    float inv = 1.f / s;
    #pragma unroll
    for (int e = 0; e < NE; e++) p[e] *= inv;
    // top-2, ties -> lower index (matches jax.lax.top_k)
    int e0 = 0;
    #pragma unroll
    for (int e = 1; e < NE; e++) if (p[e] > p[e0]) e0 = e;
    int e1 = (e0 == 0) ? 1 : 0;
    #pragma unroll
    for (int e = 0; e < NE; e++) if (e != e0 && p[e] > p[e1]) e1 = e;

    if (lane < NE) atomicAdd(Psum + lane, p[lane]);
    if (lane == 0) {
        int p0 = atomicAdd(cnt + e0, 1);
        idx_buf[e0*Ntok + p0] = n;              // k=0
        int p1 = atomicAdd(cnt + e1, 1);
        idx_buf[e1*Ntok + p1] = n | 0x10000;    // k=1 flag in bit 16
        wts[2*n]   = p[e0];
        wts[2*n+1] = p[e1];
    }
}

// ---------------- aux loss ----------------
__global__ void aux_kernel(const int* __restrict__ cnt, const float* __restrict__ Psum,
                           const int* __restrict__ dtf, void* __restrict__ out)
{
    if (threadIdx.x == 0) {
        float s = 0.f;
        for (int e = 0; e < NE; e++) s += (float)cnt[e] * Psum[e];
        float a = 0.08f * s / (16384.f * 8192.f);
        if (*dtf) ((float*)out)[(size_t)Ntok * Dm] = a;
        else      ((bf16*)out)[(size_t)Ntok * Dm] = f2b(a);
    }
}

// ---------------- transpose: src[R][C] -> dst[C][R] (bf16 out), per-expert blockIdx.z ----------------
__global__ void transpose_kernel(const void* __restrict__ srcv, bf16* __restrict__ dst,
                                 int R, int C, const int* __restrict__ dtf)
{
    __shared__ bf16 t[32][33];
    int fp32 = *dtf;
    size_t base = (size_t)blockIdx.z * R * C;
    int c0 = blockIdx.x * 32, r0 = blockIdx.y * 32;
    int tx = threadIdx.x, ty = threadIdx.y;
    if (fp32) {
        const float* src = (const float*)srcv;
        #pragma unroll
        for (int i = 0; i < 4; i++)
            t[ty + 8*i][tx] = f2b(src[base + (size_t)(r0 + ty + 8*i) * C + c0 + tx]);
    } else {
        const bf16* src = (const bf16*)srcv;
        #pragma unroll
        for (int i = 0; i < 4; i++)
            t[ty + 8*i][tx] = src[base + (size_t)(r0 + ty + 8*i) * C + c0 + tx];
    }
    __syncthreads();
    #pragma unroll
    for (int i = 0; i < 4; i++)
        dst[base + (size_t)(c0 + ty + 8*i) * R + r0 + tx] = t[tx][ty + 8*i];
}

// ---------------- ffn1: h = silu(xg@W1+b1) * (xg@W3+b3), gathered rows ----------------
__global__ __launch_bounds__(256) void ffn1_kernel(
    const void* __restrict__ xv, const bf16* __restrict__ w1t, const bf16* __restrict__ w3t,
    const void* __restrict__ b1v, const void* __restrict__ b3v, const int* __restrict__ dtf,
    const int* __restrict__ cnt, const int* __restrict__ idx_buf, bf16* __restrict__ hbuf)
{
    int e = blockIdx.z;
    int c = cnt[e];
    int m0 = blockIdx.y * 64;
    if (m0 >= c) return;
    int h0 = blockIdx.x * 128;
    int fp32 = *dtf;

    __shared__ __align__(16) bf16 aL[64][32];
    __shared__ __align__(16) bf16 bL1[128][32];
    __shared__ __align__(16) bf16 bL3[128][32];
    __shared__ int tk[64];
    __shared__ int rl[64];

    int tid = threadIdx.x;
    if (tid < 64) {
        int m = m0 + tid; if (m > c - 1) m = c - 1;
        int v = idx_buf[e*Ntok + m];
        int n = v & 0xffff;
        tk[tid] = n;
        rl[tid] = 2*n + (v >> 16);
    }
    __syncthreads();

    const bf16* w1e = w1t + (size_t)e * Hm * Dm;
    const bf16* w3e = w3t + (size_t)e * Hm * Dm;

    int lane = tid & 63, wv = tid >> 6;
    int mrow = lane & 15, kg = lane >> 4;
    int arow = tid >> 2, akg = tid & 3;
    int tok  = tk[arow];

    f32x4 acc1[4][2], acc3[4][2];
    f32x4 z = {0.f, 0.f, 0.f, 0.f};
    #pragma unroll
    for (int ms = 0; ms < 4; ms++)
        #pragma unroll
        for (int ns = 0; ns < 2; ns++) { acc1[ms][ns] = z; acc3[ms][ns] = z; }

    for (int k0 = 0; k0 < Dm; k0 += 32) {
        if (fp32) {
            const float* xr = (const float*)xv + (size_t)tok * Dm + k0 + akg*8;
            float4 v0 = *(const float4*)xr, v1 = *(const float4*)(xr + 4);
            bf16 t8[8] = { f2b(v0.x), f2b(v0.y), f2b(v0.z), f2b(v0.w),
                           f2b(v1.x), f2b(v1.y), f2b(v1.z), f2b(v1.w) };
            *(uint4*)&aL[arow][akg*8] = *(uint4*)t8;
        } else {
            *(uint4*)&aL[arow][akg*8] =
                *(const uint4*)((const bf16*)xv + (size_t)tok * Dm + k0 + akg*8);
        }
        int c0i = tid, c1i = tid + 256;
        *(uint4*)&bL1[c0i>>2][(c0i&3)*8] = *(const uint4*)(w1e + (size_t)(h0 + (c0i>>2))*Dm + k0 + (c0i&3)*8);
        *(uint4*)&bL1[c1i>>2][(c1i&3)*8] = *(const uint4*)(w1e + (size_t)(h0 + (c1i>>2))*Dm + k0 + (c1i&3)*8);
        *(uint4*)&bL3[c0i>>2][(c0i&3)*8] = *(const uint4*)(w3e + (size_t)(h0 + (c0i>>2))*Dm + k0 + (c0i&3)*8);
        *(uint4*)&bL3[c1i>>2][(c1i&3)*8] = *(const uint4*)(w3e + (size_t)(h0 + (c1i>>2))*Dm + k0 + (c1i&3)*8);
        __syncthreads();

        short8 af[4];
        #pragma unroll
        for (int ms = 0; ms < 4; ms++)
            af[ms] = *(const short8*)&aL[ms*16 + mrow][kg*8];
        short8 bf1[2], bf3[2];
        #pragma unroll
        for (int ns = 0; ns < 2; ns++) {
            bf1[ns] = *(const short8*)&bL1[wv*32 + ns*16 + mrow][kg*8];
            bf3[ns] = *(const short8*)&bL3[wv*32 + ns*16 + mrow][kg*8];
        }
        #pragma unroll
        for (int ms = 0; ms < 4; ms++)
            #pragma unroll
            for (int ns = 0; ns < 2; ns++) {
                acc1[ms][ns] = __builtin_amdgcn_mfma_f32_16x16x32_bf16(af[ms], bf1[ns], acc1[ms][ns], 0, 0, 0);
                acc3[ms][ns] = __builtin_amdgcn_mfma_f32_16x16x32_bf16(af[ms], bf3[ns], acc3[ms][ns], 0, 0, 0);
            }
        __syncthreads();
    }

    #pragma unroll
    for (int ns = 0; ns < 2; ns++) {
        int col = h0 + wv*32 + ns*16 + mrow;
        float bb1 = fp32 ? ((const float*)b1v)[e*Hm + col] : b2f(((const bf16*)b1v)[e*Hm + col]);
        float bb3 = fp32 ? ((const float*)b3v)[e*Hm + col] : b2f(((const bf16*)b3v)[e*Hm + col]);
        #pragma unroll
        for (int ms = 0; ms < 4; ms++) {
            int rbase = ms*16 + kg*4;
            #pragma unroll
            for (int r = 0; r < 4; r++) {
                int rr = rbase + r;
                if (m0 + rr < c) {
                    float v1 = acc1[ms][ns][r] + bb1;
                    float v3 = acc3[ms][ns][r] + bb3;
                    float hv = (v1 / (1.f + expf(-v1))) * v3;   // silu(v1)*v3
                    hbuf[(size_t)rl[rr]*Hm + col] = f2b(hv);
                }
            }
        }
    }
}

// ---------------- ffn2: out_slot = h @ W2 + b2 ----------------
__global__ __launch_bounds__(256) void ffn2_kernel(
    const bf16* __restrict__ hbuf, const bf16* __restrict__ w2t, const void* __restrict__ b2v,
    const int* __restrict__ dtf,
    const int* __restrict__ cnt, const int* __restrict__ idx_buf, bf16* __restrict__ outs)
{
    int e = blockIdx.z;
    int c = cnt[e];
    int m0 = blockIdx.y * 64;
    if (m0 >= c) return;
    int d0 = blockIdx.x * 128;
    int fp32 = *dtf;

    __shared__ __align__(16) bf16 aL[64][32];
    __shared__ __align__(16) bf16 bL[128][32];
    __shared__ int rl[64];

    int tid = threadIdx.x;
    if (tid < 64) {
        int m = m0 + tid; if (m > c - 1) m = c - 1;
        int v = idx_buf[e*Ntok + m];
        rl[tid] = 2*(v & 0xffff) + (v >> 16);
    }
    __syncthreads();

    const bf16* w2e = w2t + (size_t)e * Dm * Hm;

    int lane = tid & 63, wv = tid >> 6;
    int mrow = lane & 15, kg = lane >> 4;
    int arow = tid >> 2, akg = tid & 3;
    const bf16* hrow = hbuf + (size_t)rl[arow] * Hm;

    f32x4 acc[4][2];
    f32x4 z = {0.f, 0.f, 0.f, 0.f};
    #pragma unroll
    for (int ms = 0; ms < 4; ms++)
        #pragma unroll
        for (int ns = 0; ns < 2; ns++) acc[ms][ns] = z;

    for (int k0 = 0; k0 < Hm; k0 += 32) {
        *(uint4*)&aL[arow][akg*8] = *(const uint4*)(hrow + k0 + akg*8);
        int c0i = tid, c1i = tid + 256;
        *(uint4*)&bL[c0i>>2][(c0i&3)*8] = *(const uint4*)(w2e + (size_t)(d0 + (c0i>>2))*Hm + k0 + (c0i&3)*8);
        *(uint4*)&bL[c1i>>2][(c1i&3)*8] = *(const uint4*)(w2e + (size_t)(d0 + (c1i>>2))*Hm + k0 + (c1i&3)*8);
        __syncthreads();

        short8 af[4];
        #pragma unroll
        for (int ms = 0; ms < 4; ms++)
            af[ms] = *(const short8*)&aL[ms*16 + mrow][kg*8];
        short8 bfr[2];
        #pragma unroll
        for (int ns = 0; ns < 2; ns++)
            bfr[ns] = *(const short8*)&bL[wv*32 + ns*16 + mrow][kg*8];
        #pragma unroll
        for (int ms = 0; ms < 4; ms++)
            #pragma unroll
            for (int ns = 0; ns < 2; ns++)
                acc[ms][ns] = __builtin_amdgcn_mfma_f32_16x16x32_bf16(af[ms], bfr[ns], acc[ms][ns], 0, 0, 0);
        __syncthreads();
    }

    #pragma unroll
    for (int ns = 0; ns < 2; ns++) {
        int col = d0 + wv*32 + ns*16 + mrow;
        float bb2 = fp32 ? ((const float*)b2v)[e*Dm + col] : b2f(((const bf16*)b2v)[e*Dm + col]);
        #pragma unroll
        for (int ms = 0; ms < 4; ms++) {
            int rbase = ms*16 + kg*4;
            #pragma unroll
            for (int r = 0; r < 4; r++) {
                int rr = rbase + r;
                if (m0 + rr < c)
                    outs[(size_t)rl[rr]*Dm + col] = f2b(acc[ms][ns][r] + bb2);
            }
        }
    }
}

// ---------------- combine: y[n] = w0*out[2n] + w1*out[2n+1] ----------------
__global__ void combine_kernel(const bf16* __restrict__ outs, const float* __restrict__ wts,
                               const int* __restrict__ dtf, void* __restrict__ yv)
{
    int gid = blockIdx.x * 256 + threadIdx.x;
    int n = gid >> 7;
    int j = (gid & 127) * 8;
    float w0 = wts[2*n], w1 = wts[2*n+1];
    bf16 ra[8], rb[8];
    *(uint4*)ra = *(const uint4*)(outs + (size_t)(2*n)   * Dm + j);
    *(uint4*)rb = *(const uint4*)(outs + (size_t)(2*n+1) * Dm + j);
    float o[8];
    #pragma unroll
    for (int t = 0; t < 8; t++)
        o[t] = w0 * b2f(ra[t]) + w1 * b2f(rb[t]);
    if (*dtf) {
        float* y = (float*)yv + (size_t)n * Dm + j;
        *(float4*)y       = make_float4(o[0], o[1], o[2], o[3]);
        *(float4*)(y + 4) = make_float4(o[4], o[5], o[6], o[7]);
    } else {
        bf16 ro[8];
        #pragma unroll
        for (int t = 0; t < 8; t++) ro[t] = f2b(o[t]);
        *(uint4*)((bf16*)yv + (size_t)n * Dm + j) = *(uint4*)ro;
    }
}

extern "C" void kernel_launch(void* const* d_in, const int* in_sizes, int n_in,
                              void* d_out, int out_size, void* d_ws, size_t ws_size,
                              hipStream_t stream)
{
    (void)in_sizes; (void)n_in; (void)out_size; (void)ws_size;
    const void* x  = d_in[0];
    const void* Wg = d_in[1];
    const void* W1 = d_in[2];
    const void* b1 = d_in[3];
    const void* W2 = d_in[4];
    const void* b2 = d_in[5];
    const void* W3 = d_in[6];
    const void* b3 = d_in[7];

    char* ws = (char*)d_ws;
    int*   cnt  = (int*)ws;                      // [0,32)
    int*   dtf  = (int*)(ws + 64);               // dtype flag
    float* Psum = (float*)(ws + 256);            // [256,288)
    float* wts  = (float*)(ws + 4096);           // 64 KB -> 69632
    int*   idx  = (int*)(ws + 69632);            // 256 KB -> 331776
    bf16* bufA  = (bf16*)(ws + 331776);          // 32 MiB -> 33886208  (w1t, then w2t)
    bf16* bufB  = (bf16*)(ws + 33886208);        // 32 MiB -> 67440640  (w3t, then outs)
    bf16* hbuf  = (bf16*)(ws + 67440640);        // 64 MiB -> 134549504 (~128.3 MiB total)
    bf16* outs  = bufB;

    hipMemsetAsync(d_ws, 0, 4096, stream);
    detect_kernel<<<1, 64, 0, stream>>>((const unsigned*)x, dtf);
    gate_kernel<<<Ntok/4, 256, 0, stream>>>(x, Wg, dtf, cnt, Psum, wts, idx);
    aux_kernel<<<1, 64, 0, stream>>>(cnt, Psum, dtf, d_out);
    transpose_kernel<<<dim3(Hm/32, Dm/32, NE), dim3(32, 8), 0, stream>>>(W1, bufA, Dm, Hm, dtf);
    transpose_kernel<<<dim3(Hm/32, Dm/32, NE), dim3(32, 8), 0, stream>>>(W3, bufB, Dm, Hm, dtf);
    ffn1_kernel<<<dim3(Hm/128, Ntok/64, NE), 256, 0, stream>>>(x, bufA, bufB, b1, b3, dtf, cnt, idx, hbuf);
    transpose_kernel<<<dim3(Dm/32, Hm/32, NE), dim3(32, 8), 0, stream>>>(W2, bufA, Hm, Dm, dtf);
    ffn2_kernel<<<dim3(Dm/128, Ntok/64, NE), 256, 0, stream>>>(hbuf, bufA, b2, dtf, cnt, idx, outs);
    combine_kernel<<<(Ntok*Dm/8)/256, 256, 0, stream>>>(outs, wts, dtf, d_out);
}

// Round 3
// 813.266 us; speedup vs baseline: 1.0427x; 1.0427x over previous
//
#include <hip/hip_runtime.h>
#include <hip/hip_bf16.h>
#include <math.h>

#define Ntok 8192
#define Dm   1024
#define Hm   2048
#define NE   8

typedef __hip_bfloat16 bf16;
typedef __attribute__((ext_vector_type(8))) short short8;
typedef __attribute__((ext_vector_type(4))) float f32x4;

static __device__ __forceinline__ float b2f(bf16 v){ return __bfloat162float(v); }
static __device__ __forceinline__ bf16  f2b(float v){ return __float2bfloat16(v); }

// async global->LDS, 16B per lane; LDS dest must be wave-uniform base (lane i lands at base + i*16)
static __device__ __forceinline__ void gl2lds16(const bf16* g, bf16* l) {
    __builtin_amdgcn_global_load_lds(
        (const __attribute__((address_space(1))) unsigned*)(const void*)g,
        (__attribute__((address_space(3))) unsigned*)(void*)l, 16, 0, 0);
}

// ---------------- dtype detect: fp32 data has fp32-exponent <200; bf16-pairs >=~240 ----------------
__global__ void detect_kernel(const unsigned* __restrict__ xw, int* dtf)
{
    unsigned w = xw[threadIdx.x];
    int ex = (w >> 23) & 0xff;
    unsigned long long m = __ballot(ex < 200);
    if (threadIdx.x == 0) *dtf = (__popcll(m) > 32) ? 1 : 0;
}

// ---------------- gate: softmax + top-2 routing ----------------
__global__ void gate_kernel(const void* __restrict__ xv, const void* __restrict__ wgv,
                            const int* __restrict__ dtf,
                            int* cnt, float* Psum, float* wts, int* idx_buf)
{
    int fp32 = *dtf;
    int lane = threadIdx.x & 63;
    int wv   = threadIdx.x >> 6;
    int n    = blockIdx.x * 4 + wv;

    float acc[NE];
    #pragma unroll
    for (int e = 0; e < NE; e++) acc[e] = 0.f;

    if (fp32) {
        const float* xr = (const float*)xv + (size_t)n * Dm;
        const float* Wg = (const float*)wgv;
        #pragma unroll
        for (int i = 0; i < 16; i++) {
            float xval = xr[lane + 64*i];
            #pragma unroll
            for (int e = 0; e < NE; e++) acc[e] += xval * Wg[e*Dm + lane + 64*i];
        }
    } else {
        const bf16* xr = (const bf16*)xv + (size_t)n * Dm;
        const bf16* Wg = (const bf16*)wgv;
        #pragma unroll
        for (int i = 0; i < 16; i++) {
            float xval = b2f(xr[lane + 64*i]);
            #pragma unroll
            for (int e = 0; e < NE; e++) acc[e] += xval * b2f(Wg[e*Dm + lane + 64*i]);
        }
    }
    #pragma unroll
    for (int e = 0; e < NE; e++) {
        float v = acc[e];
        #pragma unroll
        for (int off = 32; off > 0; off >>= 1) v += __shfl_xor(v, off);
        acc[e] = v;
    }
    float mx = acc[0];
    #pragma unroll
    for (int e = 1; e < NE; e++) mx = fmaxf(mx, acc[e]);
    float p[NE]; float s = 0.f;
    #pragma unroll
    for (int e = 0; e < NE; e++) { p[e] = expf(acc[e] - mx); s += p[e]; }
    float inv = 1.f / s;
    #pragma unroll
    for (int e = 0; e < NE; e++) p[e] *= inv;
    int e0 = 0;
    #pragma unroll
    for (int e = 1; e < NE; e++) if (p[e] > p[e0]) e0 = e;
    int e1 = (e0 == 0) ? 1 : 0;
    #pragma unroll
    for (int e = 0; e < NE; e++) if (e != e0 && p[e] > p[e1]) e1 = e;

    if (lane < NE) atomicAdd(Psum + lane, p[lane]);
    if (lane == 0) {
        int p0 = atomicAdd(cnt + e0, 1);
        idx_buf[e0*Ntok + p0] = n;              // k=0
        int p1 = atomicAdd(cnt + e1, 1);
        idx_buf[e1*Ntok + p1] = n | 0x10000;    // k=1 flag in bit 16
        wts[2*n]   = p[e0];
        wts[2*n+1] = p[e1];
    }
}

// ---------------- aux loss + per-expert dense-slot offsets ----------------
__global__ void aux_kernel(const int* __restrict__ cnt, const float* __restrict__ Psum,
                           const int* __restrict__ dtf, int* __restrict__ offs,
                           void* __restrict__ out)
{
    if (threadIdx.x == 0) {
        float s = 0.f; int a = 0;
        for (int e = 0; e < NE; e++) {
            offs[e] = a; a += cnt[e];
            s += (float)cnt[e] * Psum[e];
        }
        float aux = 0.08f * s / (16384.f * 8192.f);
        if (*dtf) ((float*)out)[(size_t)Ntok * Dm] = aux;
        else      ((bf16*)out)[(size_t)Ntok * Dm] = f2b(aux);
    }
}

// ---------------- transpose (two sources, same shape): src[R][C] -> dst[C][R] bf16, 64x64 tiles ----------------
__global__ void transpose2_kernel(const void* __restrict__ sA, const void* __restrict__ sB,
                                  bf16* __restrict__ dA, bf16* __restrict__ dB,
                                  int R, int C, const int* __restrict__ dtf)
{
    __shared__ bf16 t[64][68];
    int mat = blockIdx.z >> 3, e = blockIdx.z & 7;
    const void* src = mat ? sB : sA;
    bf16* dst = mat ? dB : dA;
    size_t base = (size_t)e * R * C;
    int c0 = blockIdx.x * 64, r0 = blockIdx.y * 64;
    int tid = threadIdx.x;
    int lr = tid >> 4;            // 0..15
    int lc = (tid & 15) * 4;      // 0..60

    if (*dtf) {
        const float* s = (const float*)src + base;
        #pragma unroll
        for (int i = 0; i < 4; i++) {
            float4 v = *(const float4*)(s + (size_t)(r0 + lr + 16*i) * C + c0 + lc);
            t[lr+16*i][lc+0] = f2b(v.x); t[lr+16*i][lc+1] = f2b(v.y);
            t[lr+16*i][lc+2] = f2b(v.z); t[lr+16*i][lc+3] = f2b(v.w);
        }
    } else {
        const bf16* s = (const bf16*)src + base;
        #pragma unroll
        for (int i = 0; i < 4; i++) {
            bf16 v[4];
            *(uint2*)v = *(const uint2*)(s + (size_t)(r0 + lr + 16*i) * C + c0 + lc);
            t[lr+16*i][lc+0] = v[0]; t[lr+16*i][lc+1] = v[1];
            t[lr+16*i][lc+2] = v[2]; t[lr+16*i][lc+3] = v[3];
        }
    }
    __syncthreads();
    int oc = tid >> 2;            // 0..63  (output row = source column)
    int os = tid & 3;             // 16-element segment
    bf16 ov[16];
    #pragma unroll
    for (int j = 0; j < 16; j++) ov[j] = t[os*16 + j][oc];
    bf16* dp = dst + base + (size_t)(c0 + oc) * R + r0 + os*16;
    *(uint4*)dp       = *(uint4*)ov;
    *(uint4*)(dp + 8) = *(uint4*)(ov + 8);
}

// ---------------- ffn1: h = silu(xg@W1+b1) * (xg@W3+b3), dense hbuf slots ----------------
__global__ __launch_bounds__(256) void ffn1_kernel(
    const void* __restrict__ xv, const bf16* __restrict__ w1t, const bf16* __restrict__ w3t,
    const void* __restrict__ b1v, const void* __restrict__ b3v, const int* __restrict__ dtf,
    const int* __restrict__ cnt, const int* __restrict__ offs,
    const int* __restrict__ idx_buf, bf16* __restrict__ hbuf)
{
    int e = blockIdx.z;
    int c = cnt[e];
    int m0 = blockIdx.y * 64;
    if (m0 >= c) return;
    int h0 = blockIdx.x * 128;
    int fp32 = *dtf;
    int slot0 = offs[e] + m0;

    __shared__ __align__(16) bf16 aL[64][32];
    __shared__ __align__(16) bf16 bL1[128][32];
    __shared__ __align__(16) bf16 bL3[128][32];
    __shared__ int tk[64];

    int tid = threadIdx.x;
    if (tid < 64) {
        int m = m0 + tid; if (m > c - 1) m = c - 1;
        tk[tid] = idx_buf[e*Ntok + m] & 0xffff;
    }
    __syncthreads();

    const bf16* w1e = w1t + (size_t)e * Hm * Dm;
    const bf16* w3e = w3t + (size_t)e * Hm * Dm;

    int lane = tid & 63, wv = tid >> 6;
    int mrow = lane & 15, kg = lane >> 4;

    // A-tile staging through VGPR (handles fp32->bf16 convert): row tid>>2, 16B seg tid&3
    int arow = tid >> 2, aseg = tid & 3;
    const float* axf = (const float*)xv + (size_t)tk[arow] * Dm + aseg*8;
    const bf16*  axb = (const bf16*) xv + (size_t)tk[arow] * Dm + aseg*8;

    // B-tiles via async global_load_lds: wave w owns rows [32w,32w+32)
    int brow = 32*wv + (lane >> 2);
    int bseg = lane & 3;
    const bf16* g1a = w1e + (size_t)(h0 + brow     ) * Dm + bseg*8;
    const bf16* g1b = w1e + (size_t)(h0 + brow + 16) * Dm + bseg*8;
    const bf16* g3a = w3e + (size_t)(h0 + brow     ) * Dm + bseg*8;
    const bf16* g3b = w3e + (size_t)(h0 + brow + 16) * Dm + bseg*8;
    bf16* l1a = &bL1[32*wv   ][0];
    bf16* l1b = &bL1[32*wv+16][0];
    bf16* l3a = &bL3[32*wv   ][0];
    bf16* l3b = &bL3[32*wv+16][0];

    f32x4 acc1[4][2], acc3[4][2];
    f32x4 z = {0.f, 0.f, 0.f, 0.f};
    #pragma unroll
    for (int ms = 0; ms < 4; ms++)
        #pragma unroll
        for (int ns = 0; ns < 2; ns++) { acc1[ms][ns] = z; acc3[ms][ns] = z; }

    for (int k0 = 0; k0 < Dm; k0 += 32) {
        gl2lds16(g1a, l1a); gl2lds16(g1b, l1b);
        gl2lds16(g3a, l3a); gl2lds16(g3b, l3b);
        g1a += 32; g1b += 32; g3a += 32; g3b += 32;
        if (fp32) {
            float4 v0 = *(const float4*)axf;
            float4 v1 = *(const float4*)(axf + 4);
            axf += 32;
            bf16 t8[8] = { f2b(v0.x), f2b(v0.y), f2b(v0.z), f2b(v0.w),
                           f2b(v1.x), f2b(v1.y), f2b(v1.z), f2b(v1.w) };
            *(uint4*)&aL[arow][aseg*8] = *(uint4*)t8;
        } else {
            *(uint4*)&aL[arow][aseg*8] = *(const uint4*)axb;
            axb += 32;
        }
        __syncthreads();

        short8 af[4];
        #pragma unroll
        for (int ms = 0; ms < 4; ms++)
            af[ms] = *(const short8*)&aL[ms*16 + mrow][kg*8];
        short8 bf1[2], bf3[2];
        #pragma unroll
        for (int ns = 0; ns < 2; ns++) {
            bf1[ns] = *(const short8*)&bL1[wv*32 + ns*16 + mrow][kg*8];
            bf3[ns] = *(const short8*)&bL3[wv*32 + ns*16 + mrow][kg*8];
        }
        #pragma unroll
        for (int ms = 0; ms < 4; ms++)
            #pragma unroll
            for (int ns = 0; ns < 2; ns++) {
                acc1[ms][ns] = __builtin_amdgcn_mfma_f32_16x16x32_bf16(af[ms], bf1[ns], acc1[ms][ns], 0, 0, 0);
                acc3[ms][ns] = __builtin_amdgcn_mfma_f32_16x16x32_bf16(af[ms], bf3[ns], acc3[ms][ns], 0, 0, 0);
            }
        __syncthreads();
    }

    #pragma unroll
    for (int ns = 0; ns < 2; ns++) {
        int col = h0 + wv*32 + ns*16 + mrow;
        float bb1 = fp32 ? ((const float*)b1v)[e*Hm + col] : b2f(((const bf16*)b1v)[e*Hm + col]);
        float bb3 = fp32 ? ((const float*)b3v)[e*Hm + col] : b2f(((const bf16*)b3v)[e*Hm + col]);
        #pragma unroll
        for (int ms = 0; ms < 4; ms++) {
            int rbase = ms*16 + kg*4;
            #pragma unroll
            for (int r = 0; r < 4; r++) {
                int rr = rbase + r;
                if (m0 + rr < c) {
                    float v1 = acc1[ms][ns][r] + bb1;
                    float v3 = acc3[ms][ns][r] + bb3;
                    float hv = (v1 / (1.f + expf(-v1))) * v3;   // silu(v1)*v3
                    hbuf[(size_t)(slot0 + rr)*Hm + col] = f2b(hv);
                }
            }
        }
    }
}

// ---------------- ffn2: out_slot = h @ W2 + b2 (dense A, scattered output rows) ----------------
__global__ __launch_bounds__(256) void ffn2_kernel(
    const bf16* __restrict__ hbuf, const bf16* __restrict__ w2t, const void* __restrict__ b2v,
    const int* __restrict__ dtf, const int* __restrict__ cnt, const int* __restrict__ offs,
    const int* __restrict__ idx_buf, bf16* __restrict__ outs)
{
    int e = blockIdx.z;
    int c = cnt[e];
    int m0 = blockIdx.y * 64;
    if (m0 >= c) return;
    int d0 = blockIdx.x * 128;
    int fp32 = *dtf;
    int slot0 = offs[e] + m0;

    __shared__ __align__(16) bf16 aL[64][32];
    __shared__ __align__(16) bf16 bL[128][32];
    __shared__ int rl[64];

    int tid = threadIdx.x;
    if (tid < 64) {
        int m = m0 + tid; if (m > c - 1) m = c - 1;
        int v = idx_buf[e*Ntok + m];
        rl[tid] = 2*(v & 0xffff) + (v >> 16);
    }
    __syncthreads();

    const bf16* w2e = w2t + (size_t)e * Dm * Hm;

    int lane = tid & 63, wv = tid >> 6;
    int mrow = lane & 15, kg = lane >> 4;

    // A-tile via global_load_lds: dense hbuf rows slot0..slot0+63; wave w owns rows [16w,16w+16)
    int garow = slot0 + 16*wv + (lane >> 2);
    if (garow > Ntok*2 - 1) garow = Ntok*2 - 1;
    const bf16* gA = hbuf + (size_t)garow * Hm + (lane & 3)*8;
    bf16* lA = &aL[16*wv][0];

    // B-tile: wave w owns rows [32w,32w+32)
    int brow = 32*wv + (lane >> 2);
    int bseg = lane & 3;
    const bf16* g2a = w2e + (size_t)(d0 + brow     ) * Hm + bseg*8;
    const bf16* g2b = w2e + (size_t)(d0 + brow + 16) * Hm + bseg*8;
    bf16* l2a = &bL[32*wv   ][0];
    bf16* l2b = &bL[32*wv+16][0];

    f32x4 acc[4][2];
    f32x4 z = {0.f, 0.f, 0.f, 0.f};
    #pragma unroll
    for (int ms = 0; ms < 4; ms++)
        #pragma unroll
        for (int ns = 0; ns < 2; ns++) acc[ms][ns] = z;

    for (int k0 = 0; k0 < Hm; k0 += 32) {
        gl2lds16(gA, lA);
        gl2lds16(g2a, l2a); gl2lds16(g2b, l2b);
        gA += 32; g2a += 32; g2b += 32;
        __syncthreads();

        short8 af[4];
        #pragma unroll
        for (int ms = 0; ms < 4; ms++)
            af[ms] = *(const short8*)&aL[ms*16 + mrow][kg*8];
        short8 bfr[2];
        #pragma unroll
        for (int ns = 0; ns < 2; ns++)
            bfr[ns] = *(const short8*)&bL[wv*32 + ns*16 + mrow][kg*8];
        #pragma unroll
        for (int ms = 0; ms < 4; ms++)
            #pragma unroll
            for (int ns = 0; ns < 2; ns++)
                acc[ms][ns] = __builtin_amdgcn_mfma_f32_16x16x32_bf16(af[ms], bfr[ns], acc[ms][ns], 0, 0, 0);
        __syncthreads();
    }

    #pragma unroll
    for (int ns = 0; ns < 2; ns++) {
        int col = d0 + wv*32 + ns*16 + mrow;
        float bb2 = fp32 ? ((const float*)b2v)[e*Dm + col] : b2f(((const bf16*)b2v)[e*Dm + col]);
        #pragma unroll
        for (int ms = 0; ms < 4; ms++) {
            int rbase = ms*16 + kg*4;
            #pragma unroll
            for (int r = 0; r < 4; r++) {
                int rr = rbase + r;
                if (m0 + rr < c)
                    outs[(size_t)rl[rr]*Dm + col] = f2b(acc[ms][ns][r] + bb2);
            }
        }
    }
}

// ---------------- combine: y[n] = w0*out[2n] + w1*out[2n+1] ----------------
__global__ void combine_kernel(const bf16* __restrict__ outs, const float* __restrict__ wts,
                               const int* __restrict__ dtf, void* __restrict__ yv)
{
    int gid = blockIdx.x * 256 + threadIdx.x;
    int n = gid >> 7;
    int j = (gid & 127) * 8;
    float w0 = wts[2*n], w1 = wts[2*n+1];
    bf16 ra[8], rb[8];
    *(uint4*)ra = *(const uint4*)(outs + (size_t)(2*n)   * Dm + j);
    *(uint4*)rb = *(const uint4*)(outs + (size_t)(2*n+1) * Dm + j);
    float o[8];
    #pragma unroll
    for (int t = 0; t < 8; t++)
        o[t] = w0 * b2f(ra[t]) + w1 * b2f(rb[t]);
    if (*dtf) {
        float* y = (float*)yv + (size_t)n * Dm + j;
        *(float4*)y       = make_float4(o[0], o[1], o[2], o[3]);
        *(float4*)(y + 4) = make_float4(o[4], o[5], o[6], o[7]);
    } else {
        bf16 ro[8];
        #pragma unroll
        for (int t = 0; t < 8; t++) ro[t] = f2b(o[t]);
        *(uint4*)((bf16*)yv + (size_t)n * Dm + j) = *(uint4*)ro;
    }
}

extern "C" void kernel_launch(void* const* d_in, const int* in_sizes, int n_in,
                              void* d_out, int out_size, void* d_ws, size_t ws_size,
                              hipStream_t stream)
{
    (void)in_sizes; (void)n_in; (void)out_size; (void)ws_size;
    const void* x  = d_in[0];
    const void* Wg = d_in[1];
    const void* W1 = d_in[2];
    const void* b1 = d_in[3];
    const void* W2 = d_in[4];
    const void* b2 = d_in[5];
    const void* W3 = d_in[6];
    const void* b3 = d_in[7];

    char* ws = (char*)d_ws;
    int*   cnt  = (int*)ws;                      // [0,32)
    int*   dtf  = (int*)(ws + 64);               // dtype flag
    float* Psum = (float*)(ws + 256);            // [256,288)
    int*   offs = (int*)(ws + 512);              // [512,544)
    float* wts  = (float*)(ws + 4096);           // 64 KB -> 69632
    int*   idx  = (int*)(ws + 69632);            // 256 KB -> 331776
    bf16* bufA  = (bf16*)(ws + 331776);          // 32 MiB (w1t, then w2t)
    bf16* bufB  = (bf16*)(ws + 33886208);        // 32 MiB (w3t, then outs)
    bf16* hbuf  = (bf16*)(ws + 67440640);        // 64 MiB -> ends 134549504 (~128.3 MiB total)
    bf16* outs  = bufB;

    hipMemsetAsync(d_ws, 0, 4096, stream);
    detect_kernel<<<1, 64, 0, stream>>>((const unsigned*)x, dtf);
    gate_kernel<<<Ntok/4, 256, 0, stream>>>(x, Wg, dtf, cnt, Psum, wts, idx);
    aux_kernel<<<1, 64, 0, stream>>>(cnt, Psum, dtf, offs, d_out);
    // W1,W3: [D][H] -> [H][D]
    transpose2_kernel<<<dim3(Hm/64, Dm/64, 16), 256, 0, stream>>>(W1, W3, bufA, bufB, Dm, Hm, dtf);
    ffn1_kernel<<<dim3(Hm/128, Ntok/64, NE), 256, 0, stream>>>(x, bufA, bufB, b1, b3, dtf, cnt, offs, idx, hbuf);
    // W2: [H][D] -> [D][H]  (into bufA, w1t dead)
    transpose2_kernel<<<dim3(Dm/64, Hm/64, 8), 256, 0, stream>>>(W2, W2, bufA, bufA, Hm, Dm, dtf);
    ffn2_kernel<<<dim3(Dm/128, Ntok/64, NE), 256, 0, stream>>>(hbuf, bufA, b2, dtf, cnt, offs, idx, outs);
    combine_kernel<<<(Ntok*Dm/8)/256, 256, 0, stream>>>(outs, wts, dtf, d_out);
}